// Round 1
// 928.418 us; speedup vs baseline: 1.0083x; 1.0083x over previous
//
#include <hip/hip_runtime.h>

#define ENT_DIM 128
#define BATCH 262144
#define MARGIN 1.0f
#define EPS 1e-6f
#define NITER 16                       // pairs per wave
#define WAVES_PER_BLOCK 4
#define NWAVES (BATCH / NITER)         // 16384
#define NBLOCKS (NWAVES / WAVES_PER_BLOCK)  // 4096

__global__ void zero_out_kernel(float* out) {
    out[0] = 0.0f;
}

// One wave processes one (pos, neg) pair per step:
//   lanes 0-31  : pos triple (head/tail/rel rows, float4 per lane = 128 floats/row)
//   lanes 32-63 : neg triple
// Both halves share the same butterfly-reduction instructions.
__device__ __forceinline__ float pair_term(
    float4 H, float4 Hp, float4 T, float4 Tp, float4 R, float4 Rp, int lane)
{
    // partial dots: dot(head, headp), dot(tail, tailp) -- per half-wave
    float dh = H.x*Hp.x + H.y*Hp.y + H.z*Hp.z + H.w*Hp.w;
    float dt = T.x*Tp.x + T.y*Tp.y + T.z*Tp.z + T.w*Tp.w;
#pragma unroll
    for (int off = 16; off >= 1; off >>= 1) {
        dh += __shfl_xor(dh, off);     // stays within each 32-lane half
        dt += __shfl_xor(dt, off);
    }

    // d = (relp*dh + head) + rel - (relp*dt + tail) + EPS   (per component)
    float dx = Rp.x * dh + H.x + R.x - (Rp.x * dt + T.x) + EPS;
    float dy = Rp.y * dh + H.y + R.y - (Rp.y * dt + T.y) + EPS;
    float dz = Rp.z * dh + H.z + R.z - (Rp.z * dt + T.z) + EPS;
    float dw = Rp.w * dh + H.w + R.w - (Rp.w * dt + T.w) + EPS;

    float s = dx*dx + dy*dy + dz*dz + dw*dw;
#pragma unroll
    for (int off = 16; off >= 1; off >>= 1) s += __shfl_xor(s, off);
    // lower half now holds sum(d_pos^2), upper half sum(d_neg^2)

    float so = __shfl_xor(s, 32);
    float a = sqrtf(s), b = sqrtf(so);
    float v = (lane < 32) ? (a - b) : (b - a);   // sqrt(sp) - sqrt(sn) on all lanes
    return fmaxf(v + MARGIN, 0.0f);
}

// Load pair kk into buffer p. kk is a compile-time constant after unrolling,
// so the int2-component select and bpermute source lanes fold to constants.
#define LOADP(kk, p) do {                                                   \
    const int e0 = 3*(kk), e1 = 3*(kk) + 1, e2 = 3*(kk) + 2;                \
    int ih = __shfl((e0 & 1) ? ivy : ivx, (e0 >> 1) + hi32);                \
    int ir = __shfl((e1 & 1) ? ivy : ivx, (e1 >> 1) + hi32);                \
    int it = __shfl((e2 & 1) ? ivy : ivx, (e2 >> 1) + hi32);                \
    uint ho = ((uint)ih << 9) | lofs;                                       \
    uint ro = ((uint)ir << 9) | lofs;                                       \
    uint to = ((uint)it << 9) | lofs;                                       \
    H##p  = *(const float4*)(eb + ho);                                      \
    Hp##p = *(const float4*)(em + ho);                                      \
    T##p  = *(const float4*)(eb + to);                                      \
    Tp##p = *(const float4*)(em + to);                                      \
    R##p  = *(const float4*)(rb + ro);                                      \
    Rp##p = *(const float4*)(rm + ro);                                      \
} while (0)

__global__ __launch_bounds__(256, 4) void transd_kernel(
    const float* __restrict__ ent_emb,
    const float* __restrict__ ent_map,
    const float* __restrict__ rel_emb,
    const float* __restrict__ rel_map,
    const int* __restrict__ pos_x,
    const int* __restrict__ neg_x,
    float* __restrict__ out)
{
    const int lane = threadIdx.x & 63;
    const int wid  = threadIdx.x >> 6;
    const int gw   = blockIdx.x * WAVES_PER_BLOCK + wid;  // wave id: pairs [NITER*gw, NITER*gw+NITER)

    const int  hi32 = lane & 32;               // 0 for pos half, 32 for neg half
    const uint lofs = (uint)(lane & 31) << 4;  // byte offset of this lane's float4 in a row

    const char* __restrict__ eb = (const char*)ent_emb;
    const char* __restrict__ em = (const char*)ent_map;
    const char* __restrict__ rb = (const char*)rel_emb;
    const char* __restrict__ rm = (const char*)rel_map;

    // Preload this wave's 96 triple indices in one coalesced shot:
    //   lanes 0-23  : pos_x ints [48*gw .. 48*gw+48) as int2
    //   lanes 32-55 : neg_x ints likewise
    int ivx = 0, ivy = 0;
    if (lane < 24) {
        int2 t = ((const int2*)(pos_x + 3 * NITER * gw))[lane];
        ivx = t.x; ivy = t.y;
    } else if (hi32 && lane < 56) {
        int2 t = ((const int2*)(neg_x + 3 * NITER * gw))[lane - 32];
        ivx = t.x; ivy = t.y;
    }

    float4 H0, Hp0, T0, Tp0, R0, Rp0;
    float4 H1, Hp1, T1, Tp1, R1, Rp1;
    float acc = 0.0f;

    // Double-buffered: pair k+1's 6 gathers are in flight while pair k computes.
    LOADP(0, 0);
#pragma unroll
    for (int k = 0; k < NITER; k += 2) {
        LOADP(k + 1, 1);
        acc += pair_term(H0, Hp0, T0, Tp0, R0, Rp0, lane);
        if (k + 2 < NITER) LOADP(k + 2, 0);
        acc += pair_term(H1, Hp1, T1, Tp1, R1, Rp1, lane);
    }

    // All 64 lanes hold identical acc. 4 waves -> 1 atomic per block.
    __shared__ float wsum[WAVES_PER_BLOCK];
    if (lane == 0) wsum[wid] = acc;
    __syncthreads();
    if (threadIdx.x == 0) {
        float s = wsum[0] + wsum[1] + wsum[2] + wsum[3];
        atomicAdd(out, s * (1.0f / (float)BATCH));
    }
}

extern "C" void kernel_launch(void* const* d_in, const int* in_sizes, int n_in,
                              void* d_out, int out_size, void* d_ws, size_t ws_size,
                              hipStream_t stream) {
    const float* ent_emb     = (const float*)d_in[0];
    const float* ent_map_emb = (const float*)d_in[1];
    const float* rel_emb     = (const float*)d_in[2];
    const float* rel_map_emb = (const float*)d_in[3];
    const int*   pos_x       = (const int*)d_in[4];
    const int*   neg_x       = (const int*)d_in[5];
    float* out = (float*)d_out;

    hipLaunchKernelGGL(zero_out_kernel, dim3(1), dim3(1), 0, stream, out);

    hipLaunchKernelGGL(transd_kernel, dim3(NBLOCKS), dim3(256), 0, stream,
                       ent_emb, ent_map_emb, rel_emb, rel_map_emb,
                       pos_x, neg_x, out);
}